// Round 3
// baseline (305.311 us; speedup 1.0000x reference)
//
#include <hip/hip_runtime.h>
#include <hip/hip_bf16.h>

#define RR 100
#define MID 256
#define NN 384
#define KP 128   // rank padded to 128 (zeros in r=100..127)
#define OPITCH 132  // epilogue LDS row pitch (floats): +4 pad -> 2-way-only aliasing

typedef __attribute__((ext_vector_type(8))) __bf16 bf16x8;
typedef __attribute__((ext_vector_type(4))) float floatx4;
typedef unsigned short ushort_t;

// Swizzled LDS offset (elements) for row-major [128][KP] bf16 tiles stored as
// 16 chunks of 8 bf16 per row; chunk index XOR'd with (row&15) so that
// MFMA fragment reads (16 rows x same chunk) spread across all 32 banks.
#define SW(row, ch) ((((row) << 7)) + ((((ch) ^ ((row) & 15))) << 3))

__device__ __forceinline__ ushort_t f2bf(float f) {
  __hip_bfloat16 h = __float2bfloat16(f);
  return __builtin_bit_cast(ushort_t, h);
}

// ---------------- Factor nets (all three in one launch) ----------------
// blockIdx.x = row i (0..383), blockIdx.y = net (0=A, 1=B, 2=C).
// A,B written as fp32 [384][128] (pad zeros); C written as bf16 [384][128].
__global__ __launch_bounds__(256) void factors_kernel(
    const float* __restrict__ xA, const float* __restrict__ xB,
    const float* __restrict__ xC,
    const float* __restrict__ AW1, const float* __restrict__ Ab1,
    const float* __restrict__ AW2, const float* __restrict__ Ab2,
    const float* __restrict__ BW1, const float* __restrict__ Bb1,
    const float* __restrict__ BW2, const float* __restrict__ Bb2,
    const float* __restrict__ CW1, const float* __restrict__ Cb1,
    const float* __restrict__ CW2, const float* __restrict__ Cb2,
    const float* __restrict__ CW3, const float* __restrict__ Cb3,
    float* __restrict__ Af, float* __restrict__ Bf,
    ushort_t* __restrict__ Cbf) {
  __shared__ float h[MID];
  __shared__ float h2[MID];
  const int i = blockIdx.x;
  const int net = blockIdx.y;
  const int t = threadIdx.x;

  const float* x  = (net == 0) ? xA  : (net == 1) ? xB  : xC;
  const float* W1 = (net == 0) ? AW1 : (net == 1) ? BW1 : CW1;
  const float* b1 = (net == 0) ? Ab1 : (net == 1) ? Bb1 : Cb1;

  const float xv = x[i];
  h[t] = sinf(1.5f * (xv * W1[t] + b1[t]));
  __syncthreads();

  const float* hlast = h;
  if (net == 2) {  // block-uniform branch
    float acc = Cb2[t];
    const float4* __restrict__ w4 = (const float4*)&CW2[t * MID];
    const float4* __restrict__ h4 = (const float4*)h;
#pragma unroll 8
    for (int m = 0; m < MID / 4; ++m) {
      const float4 wv = w4[m];
      const float4 hv = h4[m];
      acc += hv.x * wv.x + hv.y * wv.y + hv.z * wv.z + hv.w * wv.w;
    }
    h2[t] = sinf(1.5f * acc);
    __syncthreads();
    hlast = h2;
  }

  const float* W2 = (net == 0) ? AW2 : (net == 1) ? BW2 : CW3;
  const float* b2 = (net == 0) ? Ab2 : (net == 1) ? Bb2 : Cb3;

  if (t < KP) {
    float v = 0.0f;
    if (t < RR) {
      float acc = b2[t];
      const float4* __restrict__ w4 = (const float4*)&W2[t * MID];
      const float4* __restrict__ h4 = (const float4*)hlast;
#pragma unroll 8
      for (int m = 0; m < MID / 4; ++m) {
        const float4 wv = w4[m];
        const float4 hv = h4[m];
        acc += hv.x * wv.x + hv.y * wv.y + hv.z * wv.z + hv.w * wv.w;
      }
      v = acc;
    }
    if (net == 0)      Af[i * KP + t] = v;
    else if (net == 1) Bf[i * KP + t] = v;
    else               Cbf[i * KP + t] = f2bf(v);
  }
}

// ---------------- CP contraction via bf16 MFMA ----------------
// Per block (i fixed): out[i, j0:j0+128, k0:k0+128] = W @ C^T, where
// W[jx][r] = A[i,r]*B[j0+jx,r] (fp32 product, one bf16 rounding) and
// C[kx][r] bf16. K padded to 128 with zeros. 4 waves, each a 64x64 subtile
// of 16x16x32 MFMA fragments. Epilogue transposes through LDS so global
// stores are full-row float4 (2x512B contiguous segments per wave-instr).
__global__ __launch_bounds__(256, 2) void cp_mfma(
    const float* __restrict__ Af, const float* __restrict__ Bf,
    const ushort_t* __restrict__ Cbf, float* __restrict__ out) {
  __shared__ union {
    struct {
      ushort_t Wt[128 * KP];  // 32 KB
      ushort_t Ct[128 * KP];  // 32 KB
    } s;
    float Ot[128 * OPITCH];   // 67.5 KB epilogue buffer (reuses staging LDS)
  } u;

  const int i  = blockIdx.z;
  const int j0 = blockIdx.y * 128;
  const int k0 = blockIdx.x * 128;
  const int t  = threadIdx.x;

  // ---- stage C tile: plain bf16 copy into swizzled LDS (16B chunks) ----
#pragma unroll
  for (int it = 0; it < 8; ++it) {
    const int idx = t + 256 * it;
    const int row = idx >> 4;
    const int ch  = idx & 15;
    *(uint4*)&u.s.Ct[SW(row, ch)] =
        *(const uint4*)&Cbf[(size_t)(k0 + row) * KP + ch * 8];
  }

  // ---- compute W tile: 2 threads per row, 64 r's each ----
  {
    const int jx = t >> 1;
    const int hh = t & 1;
    const float* __restrict__ arow = Af + (size_t)i * KP + hh * 64;
    const float* __restrict__ brow = Bf + (size_t)(j0 + jx) * KP + hh * 64;
#pragma unroll
    for (int c = 0; c < 8; ++c) {
      const float4 a0 = *(const float4*)(arow + c * 8);
      const float4 a1 = *(const float4*)(arow + c * 8 + 4);
      const float4 b0 = *(const float4*)(brow + c * 8);
      const float4 b1 = *(const float4*)(brow + c * 8 + 4);
      uint4 wv;
      wv.x = (unsigned)f2bf(a0.x * b0.x) | ((unsigned)f2bf(a0.y * b0.y) << 16);
      wv.y = (unsigned)f2bf(a0.z * b0.z) | ((unsigned)f2bf(a0.w * b0.w) << 16);
      wv.z = (unsigned)f2bf(a1.x * b1.x) | ((unsigned)f2bf(a1.y * b1.y) << 16);
      wv.w = (unsigned)f2bf(a1.z * b1.z) | ((unsigned)f2bf(a1.w * b1.w) << 16);
      *(uint4*)&u.s.Wt[SW(jx, hh * 8 + c)] = wv;
    }
  }
  __syncthreads();

  // ---- MFMA main loop ----
  const int lane = t & 63;
  const int w    = t >> 6;
  const int wj   = (w & 1) * 64;
  const int wk   = (w >> 1) * 64;
  const int m16  = lane & 15;
  const int g    = lane >> 4;

  floatx4 acc[4][4];
#pragma unroll
  for (int jf = 0; jf < 4; ++jf)
#pragma unroll
    for (int kf = 0; kf < 4; ++kf) acc[jf][kf] = (floatx4)0.0f;

#pragma unroll
  for (int ks = 0; ks < 4; ++ks) {
    bf16x8 af[4], bfr[4];
#pragma unroll
    for (int f = 0; f < 4; ++f) {
      af[f]  = *(const bf16x8*)&u.s.Wt[SW(wj + f * 16 + m16, ks * 4 + g)];
      bfr[f] = *(const bf16x8*)&u.s.Ct[SW(wk + f * 16 + m16, ks * 4 + g)];
    }
#pragma unroll
    for (int jf = 0; jf < 4; ++jf)
#pragma unroll
      for (int kf = 0; kf < 4; ++kf)
        acc[jf][kf] = __builtin_amdgcn_mfma_f32_16x16x32_bf16(
            af[jf], bfr[kf], acc[jf][kf], 0, 0, 0);
  }

  // ---- epilogue: acc -> LDS (transpose), then full-row float4 stores ----
  __syncthreads();  // all waves done reading Wt/Ct before overwrite

  // D layout: col(k)=m16, row(j)=g*4+r per reg.
#pragma unroll
  for (int jf = 0; jf < 4; ++jf) {
    const int jr = wj + jf * 16 + g * 4;
#pragma unroll
    for (int kf = 0; kf < 4; ++kf) {
      const int kc = wk + kf * 16 + m16;
#pragma unroll
      for (int r = 0; r < 4; ++r) {
        u.Ot[(jr + r) * OPITCH + kc] = acc[jf][kf][r];
      }
    }
  }
  __syncthreads();

  // Read back padded rows, store contiguous float4. 128x128 floats =
  // 4096 float4 chunks; 256 threads x 16 iters. Consecutive lanes ->
  // consecutive chunks -> 512B contiguous global segments.
  const size_t ibase = (size_t)i * NN * NN;
#pragma unroll
  for (int it = 0; it < 16; ++it) {
    const int c   = t + it * 256;
    const int row = c >> 5;        // 32 chunks per 128-float row
    const int c4  = (c & 31) * 4;  // float offset within row
    const float4 v = *(const float4*)&u.Ot[row * OPITCH + c4];
    *(float4*)&out[ibase + (size_t)(j0 + row) * NN + k0 + c4] = v;
  }
}

extern "C" void kernel_launch(void* const* d_in, const int* in_sizes, int n_in,
                              void* d_out, int out_size, void* d_ws, size_t ws_size,
                              hipStream_t stream) {
  const float* A_input = (const float*)d_in[0];
  const float* B_input = (const float*)d_in[1];
  const float* C_input = (const float*)d_in[2];
  const float* A_W1 = (const float*)d_in[3];
  const float* A_b1 = (const float*)d_in[4];
  const float* A_W2 = (const float*)d_in[5];
  const float* A_b2 = (const float*)d_in[6];
  const float* B_W1 = (const float*)d_in[7];
  const float* B_b1 = (const float*)d_in[8];
  const float* B_W2 = (const float*)d_in[9];
  const float* B_b2 = (const float*)d_in[10];
  const float* C_W1 = (const float*)d_in[11];
  const float* C_b1 = (const float*)d_in[12];
  const float* C_W2 = (const float*)d_in[13];
  const float* C_b2 = (const float*)d_in[14];
  const float* C_W3 = (const float*)d_in[15];
  const float* C_b3 = (const float*)d_in[16];

  // ws layout: Af fp32 [384][128] | Bf fp32 [384][128] | Cbf bf16 [384][128]
  float* Af = (float*)d_ws;                       // 196,608 B
  float* Bf = Af + NN * KP;                       // 196,608 B
  ushort_t* Cbf = (ushort_t*)(Bf + NN * KP);      //  98,304 B  (total 480 KB)

  dim3 fgrid(NN, 3);
  factors_kernel<<<fgrid, 256, 0, stream>>>(
      A_input, B_input, C_input,
      A_W1, A_b1, A_W2, A_b2,
      B_W1, B_b1, B_W2, B_b2,
      C_W1, C_b1, C_W2, C_b2, C_W3, C_b3,
      Af, Bf, Cbf);

  dim3 grid(NN / 128, NN / 128, NN);  // (k-tiles, j-tiles, i)
  cp_mfma<<<grid, 256, 0, stream>>>(Af, Bf, Cbf, (float*)d_out);
}